// Round 1
// baseline (1077.456 us; speedup 1.0000x reference)
//
#include <hip/hip_runtime.h>
#include <math.h>

#define PP 128
#define DD 128
#define RR 16384
#define EE 131072
#define TT 1024
#define FF 513

#define TAU_SCALE 46.64723032069971    /* SR / C_SOUND */
#define KDECAY   -0.0211392282f        /* LOG_GAMMA/C - AIR */
#define LOG_GAMMA -6.907755278982137f
#define TWO_PI    6.283185307179586
#define KLDS_STRIDE 132

__device__ __forceinline__ void pf_sincos(float tau, int f, float* s, float* c) {
    // phase = exp(-2*pi*i * tau * f / T); reduce in double, eval in float
    double rev = (double)tau * (double)f * (1.0 / 1024.0);
    rev -= floor(rev);
    float ang = (float)(-TWO_PI * rev);
    __sincosf(ang, s, c);
}

// ---- per-row precompute: amp_src, tau_src, amp_rec, tau_rec, dec_prop, tau_prop
__global__ void k_per_row(const float* __restrict__ rpos,
                          const float* __restrict__ spos,
                          const float* __restrict__ cpos,
                          const float* __restrict__ avg_dist,
                          float* __restrict__ per_row) {
    int r = blockIdx.x * blockDim.x + threadIdx.x;
    if (r >= RR) return;
    float x = rpos[3*r], y = rpos[3*r+1], z = rpos[3*r+2];

    float dx = x - spos[0], dy = y - spos[1], dz = z - spos[2];
    float ds = sqrtf(dx*dx + dy*dy + dz*dz);
    per_row[0*RR + r] = (1.0f/(ds*ds + 0.001f)) * expf(KDECAY * ds);
    per_row[1*RR + r] = ds * (float)TAU_SCALE;

    dx = x - cpos[0]; dy = y - cpos[1]; dz = z - cpos[2];
    float dr = sqrtf(dx*dx + dy*dy + dz*dz);
    per_row[2*RR + r] = (1.0f/(dr*dr + 0.001f)) * expf(KDECAY * dr);
    per_row[3*RR + r] = dr * (float)TAU_SCALE;

    float da = avg_dist[r];
    per_row[4*RR + r] = expf(KDECAY * da);
    per_row[5*RR + r] = da * (float)TAU_SCALE;
}

// ---- K[p][d][e] = c0[p]*basis0[d][e] + c1[p]*basis1[d][e]
__global__ void k_build_K(const float* __restrict__ absorption,
                          const float* __restrict__ scattering,
                          const int* __restrict__ object_ids,
                          const float* __restrict__ basis,
                          float* __restrict__ Kmat) {
    int idx = blockIdx.x * 256 + threadIdx.x;   // < P*D*D
    int p  = idx >> 14;
    int de = idx & 16383;
    int obj = object_ids[p];
    float refl = 1.0f - absorption[obj];
    float sc   = scattering[obj];
    Kmat[idx] = refl*sc*basis[de] + refl*(1.0f - sc)*basis[16384 + de];
}

// ---- rad init: cur = tot = amp_src * phase(tau_src)
__global__ void k_init(const float* __restrict__ per_row,
                       float* __restrict__ cur_re, float* __restrict__ cur_im,
                       float* __restrict__ tot_re, float* __restrict__ tot_im) {
    int r = blockIdx.x;
    float amp = per_row[r];
    float tau = per_row[RR + r];
    for (int f = threadIdx.x; f < FF; f += blockDim.x) {
        float s, c; pf_sincos(tau, f, &s, &c);
        float re = amp * c, im = amp * s;
        int idx = r * FF + f;
        cur_re[idx] = re; cur_im[idx] = im;
        tot_re[idx] = re; tot_im[idx] = im;
    }
}

// ---- CSR build
__global__ void k_count(const int* __restrict__ gk_row, int* __restrict__ counts) {
    int e = blockIdx.x * 256 + threadIdx.x;
    atomicAdd(&counts[gk_row[e]], 1);
}

__global__ __launch_bounds__(1024) void k_scan(const int* __restrict__ counts,
                                               int* __restrict__ row_start,
                                               int* __restrict__ cursor) {
    __shared__ int sh[1024];
    int tid = threadIdx.x;
    int base = tid * 16;
    int local[16];
    int sum = 0;
    #pragma unroll
    for (int j = 0; j < 16; j++) { local[j] = sum; sum += counts[base + j]; }
    sh[tid] = sum;
    __syncthreads();
    for (int off = 1; off < 1024; off <<= 1) {
        int v = (tid >= off) ? sh[tid - off] : 0;
        __syncthreads();
        sh[tid] += v;
        __syncthreads();
    }
    int chunk_excl = sh[tid] - sum;   // exclusive prefix of this 16-chunk
    #pragma unroll
    for (int j = 0; j < 16; j++) {
        int v = chunk_excl + local[j];
        row_start[base + j] = v;
        cursor[base + j] = v;
    }
    if (tid == 1023) row_start[RR] = chunk_excl + sum;
}

__global__ void k_scatter(const int* __restrict__ gk_row,
                          int* __restrict__ cursor, int* __restrict__ edge_idx) {
    int e = blockIdx.x * 256 + threadIdx.x;
    int pos = atomicAdd(&cursor[gk_row[e]], 1);
    edge_idx[pos] = e;
}

// ---- batched GEMM: out[p,d,f] = sum_e K[p,d,e]*in[p,e,f], fused prop multiply.
// block = 512 threads = 64 f-lanes x 8 dy groups; each thread owns 16 d rows.
__global__ __launch_bounds__(512) void k_matmul(const float* __restrict__ Kmat,
                                                const float* __restrict__ in_re,
                                                const float* __restrict__ in_im,
                                                const float* __restrict__ per_row,
                                                float* __restrict__ out_re,
                                                float* __restrict__ out_im) {
    __shared__ float Klds[128 * KLDS_STRIDE];   // transposed: Klds[e*stride + d]
    int p  = blockIdx.y;
    int f0 = blockIdx.x * 64;
    int tid = threadIdx.x;
    const float* Kp = Kmat + p * 16384;
    for (int i = tid; i < 16384; i += 512) {
        int d = i >> 7, e = i & 127;
        Klds[e * KLDS_STRIDE + d] = Kp[i];
    }
    __syncthreads();

    int fl = tid & 63;
    int dy = tid >> 6;          // wave-uniform (wave = 64 lanes)
    int f = f0 + fl;
    if (f < FF) {
        int d0 = dy * 16;
        float accr[16], acci[16];
        #pragma unroll
        for (int j = 0; j < 16; j++) { accr[j] = 0.0f; acci[j] = 0.0f; }
        const float* ir = in_re + (p * 128) * FF + f;
        const float* ii = in_im + (p * 128) * FF + f;
        for (int e = 0; e < 128; e++) {
            float vr = ir[e * FF];
            float vi = ii[e * FF];
            const float* kr = &Klds[e * KLDS_STRIDE + d0];
            #pragma unroll
            for (int j = 0; j < 16; j++) {
                float kv = kr[j];
                accr[j] += kv * vr;
                acci[j] += kv * vi;
            }
        }
        #pragma unroll
        for (int j = 0; j < 16; j++) {
            int row = p * 128 + d0 + j;
            float dec = per_row[4*RR + row];
            float tau = per_row[5*RR + row];
            float s, c; pf_sincos(tau, f, &s, &c);
            float orr = dec * (accr[j]*c - acci[j]*s);
            float oi  = dec * (accr[j]*s + acci[j]*c);
            int idx = row * FF + f;
            out_re[idx] = orr; out_im[idx] = oi;
        }
    }
}

// ---- segment sum: cur[row] = sum_edges gk_val[e]*in[gk_col[e]]; tot += cur
__global__ __launch_bounds__(512) void k_segsum(const int* __restrict__ row_start,
                                                const int* __restrict__ edge_idx,
                                                const float* __restrict__ gk_val,
                                                const int* __restrict__ gk_col,
                                                const float* __restrict__ in_re,
                                                const float* __restrict__ in_im,
                                                float* __restrict__ cur_re,
                                                float* __restrict__ cur_im,
                                                float* __restrict__ tot_re,
                                                float* __restrict__ tot_im) {
    int row = blockIdx.x;
    int s0 = row_start[row], s1 = row_start[row + 1];
    for (int f = threadIdx.x; f < FF; f += 512) {
        float ar = 0.0f, ai = 0.0f;
        for (int k = s0; k < s1; k++) {
            int e = edge_idx[k];
            float v = gk_val[e];
            int col = gk_col[e];
            ar += v * in_re[col * FF + f];
            ai += v * in_im[col * FF + f];
        }
        int idx = row * FF + f;
        cur_re[idx] = ar; cur_im[idx] = ai;
        tot_re[idx] += ar; tot_im[idx] += ai;
    }
}

// ---- receiver reduction: echo[f] = sum_r amp_rec*phase(tau_rec)*tot[r,f]
__global__ void k_reduce(const float* __restrict__ tot_re,
                         const float* __restrict__ tot_im,
                         const float* __restrict__ per_row,
                         float* __restrict__ echo) {
    int fl = threadIdx.x & 63, ry = threadIdx.x >> 6;
    int f = blockIdx.x * 64 + fl;
    bool valid = (f < FF);
    float ar = 0.0f, ai = 0.0f;
    if (valid) {
        int rbase = blockIdx.y * 512;
        for (int k = ry; k < 512; k += 4) {
            int r = rbase + k;
            float amp = per_row[2*RR + r];
            float tau = per_row[3*RR + r];
            float s, c; pf_sincos(tau, f, &s, &c);
            float vr = tot_re[r * FF + f], vi = tot_im[r * FF + f];
            ar += amp * (c*vr - s*vi);
            ai += amp * (c*vi + s*vr);
        }
    }
    __shared__ float red[2][4][64];
    red[0][ry][fl] = ar; red[1][ry][fl] = ai;
    __syncthreads();
    if (ry == 0 && valid) {
        float sr = red[0][0][fl] + red[0][1][fl] + red[0][2][fl] + red[0][3][fl];
        float si = red[1][0][fl] + red[1][1][fl] + red[1][2][fl] + red[1][3][fl];
        atomicAdd(&echo[2*f],     sr);
        atomicAdd(&echo[2*f + 1], si);
    }
}

// ---- irfft(n=1024) / fsm_window
__global__ void k_irfft(const float* __restrict__ echo, float* __restrict__ out) {
    int t = blockIdx.x * blockDim.x + threadIdx.x;   // 0..1023
    float acc = echo[0];                              // f=0 (real)
    float nyq = echo[2 * 512];                        // Nyquist real part
    acc += (t & 1) ? -nyq : nyq;
    for (int f = 1; f < 512; f++) {
        int m = (f * t) & 1023;
        float ang = (float)m * 0.006135923151542565f;  // 2*pi/1024
        float s, c; __sincosf(ang, &s, &c);
        acc += 2.0f * (echo[2*f]*c - echo[2*f+1]*s);
    }
    acc *= (1.0f / 1024.0f);
    float tsec = (float)t * (1.0f / 16000.0f);
    float win = expf(LOG_GAMMA * tsec);
    out[t] = acc / win;
}

extern "C" void kernel_launch(void* const* d_in, const int* in_sizes, int n_in,
                              void* d_out, int out_size, void* d_ws, size_t ws_size,
                              hipStream_t stream) {
    const float* source_pos   = (const float*)d_in[0];
    const float* receiver_pos = (const float*)d_in[1];
    const float* absorption   = (const float*)d_in[2];
    const float* scattering   = (const float*)d_in[3];
    const float* gk_val       = (const float*)d_in[4];
    const float* basis        = (const float*)d_in[5];
    const float* avg_dist     = (const float*)d_in[6];
    const float* rpos         = (const float*)d_in[7];
    const int*   gk_row       = (const int*)d_in[8];
    const int*   gk_col       = (const int*)d_in[9];
    const int*   object_ids   = (const int*)d_in[10];
    float* out = (float*)d_out;

    char* base = (char*)d_ws;
    size_t off = 0;
    auto alloc = [&](size_t bytes) -> void* {
        void* ptr = base + off;
        off = (off + bytes + 255) & ~(size_t)255;
        return ptr;
    };
    const size_t RF = (size_t)RR * FF;
    float* Kmat    = (float*)alloc(sizeof(float) * PP * DD * DD);
    float* cur_re  = (float*)alloc(sizeof(float) * RF);
    float* cur_im  = (float*)alloc(sizeof(float) * RF);
    float* nxt_re  = (float*)alloc(sizeof(float) * RF);
    float* nxt_im  = (float*)alloc(sizeof(float) * RF);
    float* tot_re  = (float*)alloc(sizeof(float) * RF);
    float* tot_im  = (float*)alloc(sizeof(float) * RF);
    float* per_row = (float*)alloc(sizeof(float) * 6 * RR);
    int*   counts    = (int*)alloc(sizeof(int) * RR);
    int*   row_start = (int*)alloc(sizeof(int) * (RR + 1));
    int*   cursor    = (int*)alloc(sizeof(int) * RR);
    int*   edge_idx  = (int*)alloc(sizeof(int) * EE);
    float* echo      = (float*)alloc(sizeof(float) * 2 * FF);

    hipMemsetAsync(counts, 0, sizeof(int) * RR, stream);
    hipMemsetAsync(echo, 0, sizeof(float) * 2 * FF, stream);

    k_per_row<<<RR / 256, 256, 0, stream>>>(rpos, source_pos, receiver_pos, avg_dist, per_row);
    k_build_K<<<(PP * DD * DD) / 256, 256, 0, stream>>>(absorption, scattering, object_ids, basis, Kmat);
    k_init<<<RR, 256, 0, stream>>>(per_row, cur_re, cur_im, tot_re, tot_im);
    k_count<<<EE / 256, 256, 0, stream>>>(gk_row, counts);
    k_scan<<<1, 1024, 0, stream>>>(counts, row_start, cursor);
    k_scatter<<<EE / 256, 256, 0, stream>>>(gk_row, cursor, edge_idx);

    for (int b = 0; b < 4; b++) {
        k_matmul<<<dim3(9, PP), 512, 0, stream>>>(Kmat, cur_re, cur_im, per_row, nxt_re, nxt_im);
        k_segsum<<<RR, 512, 0, stream>>>(row_start, edge_idx, gk_val, gk_col,
                                         nxt_re, nxt_im, cur_re, cur_im, tot_re, tot_im);
    }

    k_reduce<<<dim3(9, 32), 256, 0, stream>>>(tot_re, tot_im, per_row, echo);
    k_irfft<<<4, 256, 0, stream>>>(echo, out);
}